// Round 10
// baseline (625.172 us; speedup 1.0000x reference)
//
#include <hip/hip_runtime.h>
#include <hip/hip_bf16.h>

#define NN 10000
#define KP 10048           // NN padded to multiple of 64
static constexpr float INV_C = 1.0f / 16.0f;

typedef __attribute__((ext_vector_type(8))) short bf16x8;
typedef __attribute__((ext_vector_type(4))) float f32x4;
typedef unsigned short u16;
typedef unsigned int u32;

__device__ __forceinline__ u16 f2b(float f) {
    return __builtin_bit_cast(u16, __float2bfloat16(f));
}
__device__ __forceinline__ float b2f(u16 b) {
    union { u32 u; float f; } v; v.u = ((u32)b) << 16;
    return v.f;
}
__device__ __forceinline__ bf16x8 pack8(f32x4 a, f32x4 b) {
    bf16x8 o;
    o[0]=f2b(a[0]); o[1]=f2b(a[1]); o[2]=f2b(a[2]); o[3]=f2b(a[3]);
    o[4]=f2b(b[0]); o[5]=f2b(b[1]); o[6]=f2b(b[2]); o[7]=f2b(b[3]);
    return o;
}

#define AS1(p) ((__attribute__((address_space(1))) void*)(p))
#define AS3(p) ((__attribute__((address_space(3))) void*)(p))

// ---------------------------------------------------------------
// cvt_feat: fp32 [NN][512] -> bf16; grid 2500
// ---------------------------------------------------------------
__global__ __launch_bounds__(256)
void cvt_feat(const float* __restrict__ src, u16* __restrict__ dst)
{
    int c = blockIdx.x * 256 + threadIdx.x;
    size_t base = (size_t)c * 8;
    f32x4 a = *(const f32x4*)(src + base);
    f32x4 b = *(const f32x4*)(src + base + 4);
    *(bf16x8*)(dst + base) = pack8(a, b);
}

// ---------------------------------------------------------------
// w1t: W1T fp32 [256][512] <- W1 [512][256]; grid 512
// ---------------------------------------------------------------
__global__ __launch_bounds__(256)
void w1t(const float* __restrict__ W1, float* __restrict__ W1T)
{
    int idx = blockIdx.x * 256 + threadIdx.x;
    int n = idx >> 9, k = idx & 511;
    W1T[idx] = W1[(size_t)k * 256 + n];
}

// ---------------------------------------------------------------
// Generic MFMA GEMM: C[M][N] = A(fp32)[M][lda] @ BT^T, BT bf16 [N][ldb].
// BM=64, BN=256, BK=64; 256 thr = 4 waves. (XWT pass; fallback.)
// ---------------------------------------------------------------
template<int BIAS, int RELU>
__global__ __launch_bounds__(256)
void gemm_a32_bt16(const float* __restrict__ A, int lda, int M, int Ka,
                   const u16* __restrict__ BT, int ldb, int N, int npad,
                   const float* __restrict__ bias,
                   u16* __restrict__ C, int ldc, int K)
{
    __shared__ u16 Asm[64 * 64];
    __shared__ u16 Bsm[256 * 64];
    const int t = threadIdx.x;
    const int lane = t & 63;
    const int w = t >> 6;
    const int row0 = blockIdx.x * 64;
    const int n0 = blockIdx.y * 256;

    const f32x4 fz = {0.f, 0.f, 0.f, 0.f};
    f32x4 acc[4][4];
#pragma unroll
    for (int i = 0; i < 4; ++i)
#pragma unroll
        for (int j = 0; j < 4; ++j) acc[i][j] = fz;

    const int ar = t >> 2, akq = t & 3;
    int agr = row0 + ar; if (agr > M - 1) agr = M - 1;
    const float* asrc = A + (size_t)agr * lda + akq * 16;
    const int aslot0 = (akq * 2) ^ (ar & 7);
    const int aslot1 = (akq * 2 + 1) ^ (ar & 7);
    const int l8 = lane >> 3, sl = lane & 7;

    for (int k0 = 0; k0 < K; k0 += 64) {
        bool aval = (k0 + akq * 16) < Ka;
        f32x4 x0, x1, x2, x3;
        if (aval) {
            x0 = *(const f32x4*)(asrc + k0);
            x1 = *(const f32x4*)(asrc + k0 + 4);
            x2 = *(const f32x4*)(asrc + k0 + 8);
            x3 = *(const f32x4*)(asrc + k0 + 12);
        } else {
            x0 = x1 = x2 = x3 = fz;
        }
#pragma unroll
        for (int i = 0; i < 8; ++i) {
            int lr = i * 32 + w * 8 + l8;
            int gn = n0 + lr; if (gn > N - 1) gn = N - 1;
            int ss = sl ^ (lr & 7);
            const u16* src = BT + (size_t)gn * ldb + k0 + ss * 8;
            __builtin_amdgcn_global_load_lds(AS1(src), AS3(&Bsm[(i * 32 + w * 8) * 64]),
                                             16, 0, 0);
        }
        *(bf16x8*)&Asm[ar * 64 + aslot0 * 8] = pack8(x0, x1);
        *(bf16x8*)&Asm[ar * 64 + aslot1 * 8] = pack8(x2, x3);
        __syncthreads();
#pragma unroll
        for (int kk = 0; kk < 2; ++kk) {
            bf16x8 afr[4], bfr[4];
#pragma unroll
            for (int mi = 0; mi < 4; ++mi) {
                int r = mi * 16 + (lane & 15);
                int s2 = (kk * 4 + (lane >> 4)) ^ (r & 7);
                afr[mi] = *(const bf16x8*)&Asm[r * 64 + s2 * 8];
            }
#pragma unroll
            for (int ni = 0; ni < 4; ++ni) {
                int nr = w * 64 + ni * 16 + (lane & 15);
                int s2 = (kk * 4 + (lane >> 4)) ^ (nr & 7);
                bfr[ni] = *(const bf16x8*)&Bsm[nr * 64 + s2 * 8];
            }
#pragma unroll
            for (int mi = 0; mi < 4; ++mi)
#pragma unroll
                for (int ni = 0; ni < 4; ++ni)
                    acc[mi][ni] = __builtin_amdgcn_mfma_f32_16x16x32_bf16(
                        afr[mi], bfr[ni], acc[mi][ni], 0, 0, 0);
        }
        __syncthreads();
    }
#pragma unroll
    for (int mi = 0; mi < 4; ++mi) {
        int grb = row0 + mi * 16 + (lane >> 4) * 4;
#pragma unroll
        for (int ni = 0; ni < 4; ++ni) {
            int gc = n0 + w * 64 + ni * 16 + (lane & 15);
            if (gc < npad) {
                float bv = (BIAS && gc < N) ? bias[gc] : 0.f;
#pragma unroll
                for (int rg = 0; rg < 4; ++rg) {
                    int gr = grb + rg;
                    if (gr < M) {
                        float v = acc[mi][ni][rg] + bv;
                        if (RELU) v = fmaxf(v, 0.f);
                        C[(size_t)gr * ldc + gc] = f2b(gc < N ? v : 0.f);
                    }
                }
            }
        }
    }
}

// ---------------------------------------------------------------
// gemm_na: 13-way split-K over normed_adj. Counted-vmcnt pipeline:
// raw s_barrier + s_waitcnt vmcnt(4) keeps the 4 A-prefetch loads in
// flight ACROSS both barriers (T4; __syncthreads would drain them).
// Invariant: exactly 8 B gload_lds + 4 A loads issued per iteration.
// Pws[s][NN][256] bf16 partials. grid (157, 13).
// ---------------------------------------------------------------
__global__ __launch_bounds__(256)
void gemm_na(const float* __restrict__ A, const u16* __restrict__ BT,
             u16* __restrict__ Pws)
{
    __shared__ u16 Asm[64 * 64];
    __shared__ u16 Bsm[256 * 64];
    const int t = threadIdx.x;
    const int lane = t & 63;
    const int w = t >> 6;
    const int row0 = blockIdx.x * 64;
    const int s = blockIdx.y;
    const int c0 = (157 * s) / 13, c1 = (157 * (s + 1)) / 13;

    const f32x4 fz = {0.f, 0.f, 0.f, 0.f};
    f32x4 acc[4][4];
#pragma unroll
    for (int i = 0; i < 4; ++i)
#pragma unroll
        for (int j = 0; j < 4; ++j) acc[i][j] = fz;

    const int ar = t >> 2, akq = t & 3;
    const int grow = row0 + ar;
    const int agr = grow < NN ? grow : NN - 1;
    const float* asrc = A + (size_t)agr * NN + akq * 16;
    const int aslot0 = (akq * 2) ^ (ar & 7);
    const int aslot1 = (akq * 2 + 1) ^ (ar & 7);
    const int l8 = lane >> 3, sl = lane & 7;

    // prologue: A(c0) — always in-range (c0*64 + akq*16 + 16 <= 9280 < NN)
    f32x4 x0 = *(const f32x4*)(asrc + c0 * 64);
    f32x4 x1 = *(const f32x4*)(asrc + c0 * 64 + 4);
    f32x4 x2 = *(const f32x4*)(asrc + c0 * 64 + 8);
    f32x4 x3 = *(const f32x4*)(asrc + c0 * 64 + 12);
    bool curv = true;

    for (int ck = c0; ck < c1; ++ck) {
        const int k0 = ck * 64;
        // ---- B stage: the 8 OLDEST vmem ops of this iteration ----
#pragma unroll
        for (int i = 0; i < 8; ++i) {
            int lr = i * 32 + w * 8 + l8;
            int ss = sl ^ (lr & 7);
            const u16* src = BT + (size_t)lr * KP + k0 + ss * 8;
            __builtin_amdgcn_global_load_lds(AS1(src),
                AS3(&Bsm[(i * 32 + w * 8) * 64]), 16, 0, 0);
        }
        __builtin_amdgcn_sched_barrier(0);   // pin B-before-A issue order
        // ---- A prefetch: exactly 4 loads, clamped-safe address ----
        const int knr = (ck + 1 < c1) ? (ck + 1) * 64 : c0 * 64;
        const bool nval = (ck + 1 < c1) && (knr + akq * 16 < NN);
        const int ksafe = (knr + akq * 16 < NN) ? knr : 0;
        f32x4 n0 = *(const f32x4*)(asrc + ksafe);
        f32x4 n1 = *(const f32x4*)(asrc + ksafe + 4);
        f32x4 n2 = *(const f32x4*)(asrc + ksafe + 8);
        f32x4 n3 = *(const f32x4*)(asrc + ksafe + 12);
        // ---- cvt + ds_write current A (compiler waits for x-regs) ----
        f32x4 y0 = curv ? x0 : fz, y1 = curv ? x1 : fz;
        f32x4 y2 = curv ? x2 : fz, y3 = curv ? x3 : fz;
        *(bf16x8*)&Asm[ar * 64 + aslot0 * 8] = pack8(y0, y1);
        *(bf16x8*)&Asm[ar * 64 + aslot1 * 8] = pack8(y2, y3);
        // retire the 8 B gload_lds + own ds_writes; A-prefetch stays flying
        asm volatile("s_waitcnt vmcnt(4) lgkmcnt(0)" ::: "memory");
        __builtin_amdgcn_s_barrier();
        __builtin_amdgcn_sched_barrier(0);
#pragma unroll
        for (int kk = 0; kk < 2; ++kk) {
            bf16x8 afr[4], bfr[4];
#pragma unroll
            for (int mi = 0; mi < 4; ++mi) {
                int r = mi * 16 + (lane & 15);
                int s2 = (kk * 4 + (lane >> 4)) ^ (r & 7);
                afr[mi] = *(const bf16x8*)&Asm[r * 64 + s2 * 8];
            }
#pragma unroll
            for (int ni = 0; ni < 4; ++ni) {
                int nr = w * 64 + ni * 16 + (lane & 15);
                int s2 = (kk * 4 + (lane >> 4)) ^ (nr & 7);
                bfr[ni] = *(const bf16x8*)&Bsm[nr * 64 + s2 * 8];
            }
#pragma unroll
            for (int mi = 0; mi < 4; ++mi)
#pragma unroll
                for (int ni = 0; ni < 4; ++ni)
                    acc[mi][ni] = __builtin_amdgcn_mfma_f32_16x16x32_bf16(
                        afr[mi], bfr[ni], acc[mi][ni], 0, 0, 0);
        }
        // LDS reads done (lgkm only) — do NOT drain vmcnt here
        asm volatile("s_waitcnt lgkmcnt(0)" ::: "memory");
        __builtin_amdgcn_s_barrier();
        x0 = n0; x1 = n1; x2 = n2; x3 = n3; curv = nval;
    }
    u16* outp = Pws + (size_t)s * NN * 256;
#pragma unroll
    for (int mi = 0; mi < 4; ++mi) {
        int grb = row0 + mi * 16 + (lane >> 4) * 4;
#pragma unroll
        for (int ni = 0; ni < 4; ++ni) {
            int gc = w * 64 + ni * 16 + (lane & 15);
#pragma unroll
            for (int rg = 0; rg < 4; ++rg) {
                int gr = grb + rg;
                if (gr < NN)
                    outp[(size_t)gr * 256 + gc] = f2b(acc[mi][ni][rg]);
            }
        }
    }
}

// ---------------------------------------------------------------
// reduce_h2: h = relu(sum_{s<NS} Pws[s] + b1); hw2T = (h@W2)^T bf16,
// pads 0. grid 1251, 8 rows/block (32 lanes/row).
// ---------------------------------------------------------------
template<int NS>
__global__ __launch_bounds__(256)
void reduce_h2(const u16* __restrict__ Pws, const float* __restrict__ b1,
               const float* __restrict__ W2, u16* __restrict__ hw2T)
{
    __shared__ float W2s[256 * 16];
    const int t = threadIdx.x;
#pragma unroll
    for (int i = 0; i < 16; ++i) W2s[t + i * 256] = W2[t + i * 256];
    __syncthreads();
    if (blockIdx.x == 1250) {
        if (t < 48 * 16) {
            int r = NN + (t >> 4), c = t & 15;
            hw2T[(size_t)c * KP + r] = 0;
        }
        return;
    }
    const int l = t & 31;
    const int rg = t >> 5;
    const int row = blockIdx.x * 8 + rg;
    const size_t base = (size_t)row * 256 + l * 8;
    float v[8];
#pragma unroll
    for (int j = 0; j < 8; ++j) v[j] = b1[l * 8 + j];
#pragma unroll
    for (int s = 0; s < NS; ++s) {
        bf16x8 p = *(const bf16x8*)(Pws + (size_t)s * NN * 256 + base);
#pragma unroll
        for (int j = 0; j < 8; ++j) v[j] += b2f((u16)p[j]);
    }
#pragma unroll
    for (int j = 0; j < 8; ++j) v[j] = fmaxf(v[j], 0.f);
    float o[16];
#pragma unroll
    for (int c = 0; c < 16; ++c) o[c] = 0.f;
#pragma unroll
    for (int m = 0; m < 8; ++m) {
        float x = v[m];
        const float* wrow = &W2s[(l * 8 + m) * 16];
#pragma unroll
        for (int c = 0; c < 16; ++c) o[c] += x * wrow[c];
    }
#pragma unroll
    for (int m = 1; m <= 16; m <<= 1)
#pragma unroll
        for (int c = 0; c < 16; ++c) o[c] += __shfl_xor(o[c], m, 32);
    if (l < 16)
        hw2T[(size_t)l * KP + row] = f2b(o[l]);
}

// ---------------------------------------------------------------
// adj16: Pout[s][i][c] = sum_{j in s-range} A[i][j] * BT[c][j]
// 16-way split (grid (157,16)). AFP32: fp32 A (on-the-fly cvt) else
// bf16 [*,KP]. CVT: write bf16 copy (pads zeroed). Dual accumulators.
// ---------------------------------------------------------------
template<int AFP32, int CVT>
__global__ __launch_bounds__(256)
void adj16(const void* __restrict__ Av, long lda,
           const u16* __restrict__ BT,
           float* __restrict__ Pout, int nch, int nchf,
           u16* __restrict__ Acvt)
{
    const int t = threadIdx.x, lane = t & 63, w = t >> 6;
    const int s = blockIdx.y;
    const int rowu = blockIdx.x * 64 + w * 16 + (lane & 15);
    const int row = rowu < NN ? rowu : NN - 1;
    const int kq = (lane >> 4) * 8;
    const u16* brow = BT + (size_t)(lane & 15) * KP + kq;
    const float* a32 = (const float*)Av + (size_t)row * lda + kq;
    const u16*  a16 = (const u16*) Av + (size_t)row * lda + kq;
    u16* cvtp = CVT ? (Acvt + (size_t)rowu * KP + kq) : (u16*)0;
    const bool wok = CVT && (rowu < NN);

    int c0 = (nch * s) >> 4, c1 = (nch * (s + 1)) >> 4;
    int c1f = c1 < nchf ? c1 : nchf;
    f32x4 acc0 = {0.f, 0.f, 0.f, 0.f};
    f32x4 acc1 = {0.f, 0.f, 0.f, 0.f};
    int kc = c0;
    for (; kc + 4 <= c1f; kc += 4) {
        bf16x8 a[4], b[4];
#pragma unroll
        for (int u = 0; u < 4; ++u) {
            if (AFP32) {
                f32x4 x = *(const f32x4*)(a32 + (size_t)(kc + u) * 32);
                f32x4 y = *(const f32x4*)(a32 + (size_t)(kc + u) * 32 + 4);
                a[u] = pack8(x, y);
            } else {
                a[u] = *(const bf16x8*)(a16 + (size_t)(kc + u) * 32);
            }
            b[u] = *(const bf16x8*)(brow + (size_t)(kc + u) * 32);
        }
        if (CVT && wok) {
#pragma unroll
            for (int u = 0; u < 4; ++u)
                *(bf16x8*)(cvtp + (size_t)(kc + u) * 32) = a[u];
        }
        acc0 = __builtin_amdgcn_mfma_f32_16x16x32_bf16(a[0], b[0], acc0, 0, 0, 0);
        acc1 = __builtin_amdgcn_mfma_f32_16x16x32_bf16(a[1], b[1], acc1, 0, 0, 0);
        acc0 = __builtin_amdgcn_mfma_f32_16x16x32_bf16(a[2], b[2], acc0, 0, 0, 0);
        acc1 = __builtin_amdgcn_mfma_f32_16x16x32_bf16(a[3], b[3], acc1, 0, 0, 0);
    }
    for (; kc < c1; ++kc) {
        bf16x8 a = bf16x8{0,0,0,0,0,0,0,0};
        if (AFP32) {
            if (kc * 32 + kq < NN) {
                f32x4 x = *(const f32x4*)(a32 + (size_t)kc * 32);
                f32x4 y = *(const f32x4*)(a32 + (size_t)kc * 32 + 4);
                a = pack8(x, y);
            }
        } else {
            a = *(const bf16x8*)(a16 + (size_t)kc * 32);
        }
        if (CVT && wok)
            *(bf16x8*)(cvtp + (size_t)kc * 32) = a;
        bf16x8 b = *(const bf16x8*)(brow + (size_t)kc * 32);
        acc0 = __builtin_amdgcn_mfma_f32_16x16x32_bf16(a, b, acc0, 0, 0, 0);
    }
    int ob = blockIdx.x * 64 + w * 16 + (lane >> 4) * 4;
#pragma unroll
    for (int rg = 0; rg < 4; ++rg) {
        int orow = ob + rg;
        if (orow < NN)
            Pout[(size_t)s * (NN * 16) + (size_t)orow * 16 + (lane & 15)] =
                acc0[rg] + acc1[rg];
    }
}

// ---------------------------------------------------------------
// softmax_e_h2: 4 lanes/row, grid 157. logits = sum_{16} P + b2 ->
// E = softmax - 1/16 ; bhT = (E@H)^T bf16.
// ---------------------------------------------------------------
__global__ __launch_bounds__(256)
void softmax_e_h2(const float* __restrict__ P, const float* __restrict__ b2,
                  const float* __restrict__ H, float* __restrict__ E,
                  u16* __restrict__ bhT)
{
    __shared__ float Hs[256];
    const int t = threadIdx.x;
    Hs[t] = H[t];
    __syncthreads();
    const int l = t & 63, w = t >> 6;
    const int g = l >> 2, sub = l & 3;
    const int row = blockIdx.x * 64 + w * 16 + g;
    const bool valid = row < NN;
    float acc[16];
#pragma unroll
    for (int k = 0; k < 16; ++k) acc[k] = 0.f;
    if (valid) {
#pragma unroll
        for (int pp = 0; pp < 4; ++pp) {
            const float* pl = P + (size_t)(sub * 4 + pp) * (NN * 16)
                                + (size_t)row * 16;
#pragma unroll
            for (int q = 0; q < 4; ++q) {
                f32x4 a = *(const f32x4*)(pl + q * 4);
#pragma unroll
                for (int j = 0; j < 4; ++j) acc[q * 4 + j] += a[j];
            }
        }
        if (sub == 0) {
#pragma unroll
            for (int k = 0; k < 16; ++k) acc[k] += b2[k];
        }
    }
#pragma unroll
    for (int m = 1; m <= 2; m <<= 1)
#pragma unroll
        for (int k = 0; k < 16; ++k) acc[k] += __shfl_xor(acc[k], m, 4);
    float e[16];
    if (valid) {
        float mx = acc[0];
#pragma unroll
        for (int k = 1; k < 16; ++k) mx = fmaxf(mx, acc[k]);
        float ssum = 0.f;
#pragma unroll
        for (int k = 0; k < 16; ++k) { e[k] = __expf(acc[k] - mx); ssum += e[k]; }
        float inv = 1.f / ssum;
#pragma unroll
        for (int k = 0; k < 16; ++k) e[k] = e[k] * inv - INV_C;
        f32x4 eq = {e[sub*4+0], e[sub*4+1], e[sub*4+2], e[sub*4+3]};
        *(f32x4*)(E + (size_t)row * 16 + sub * 4) = eq;
    } else {
#pragma unroll
        for (int k = 0; k < 16; ++k) e[k] = 0.f;
    }
    float o[4] = {0.f, 0.f, 0.f, 0.f};
#pragma unroll
    for (int m2 = 0; m2 < 16; ++m2) {
        float x = e[m2];
#pragma unroll
        for (int j = 0; j < 4; ++j) o[j] += x * Hs[m2 * 16 + sub * 4 + j];
    }
#pragma unroll
    for (int j = 0; j < 4; ++j)
        bhT[(size_t)(sub * 4 + j) * KP + row] = f2b(o[j]);
}

// ---------------------------------------------------------------
// combine_bmm2: B = E + sum_{16} P[s];
// LAST: out = B + 1/16 (fp32). else: bhT = (B@H)^T bf16.
// ---------------------------------------------------------------
template<int LAST>
__global__ __launch_bounds__(256)
void combine_bmm2(const float* __restrict__ E, const float* __restrict__ P,
                  const float* __restrict__ H, u16* __restrict__ bhT,
                  float* __restrict__ out)
{
    __shared__ float Hs[256];
    const int t = threadIdx.x;
    Hs[t] = H[t];
    __syncthreads();
    const int l = t & 63, w = t >> 6;
    const int g = l >> 2, sub = l & 3;
    const int row = blockIdx.x * 64 + w * 16 + g;
    const bool valid = row < NN;
    float acc[16];
#pragma unroll
    for (int k = 0; k < 16; ++k) acc[k] = 0.f;
    if (valid) {
#pragma unroll
        for (int pp = 0; pp < 4; ++pp) {
            const float* pl = P + (size_t)(sub * 4 + pp) * (NN * 16)
                                + (size_t)row * 16;
#pragma unroll
            for (int q = 0; q < 4; ++q) {
                f32x4 a = *(const f32x4*)(pl + q * 4);
#pragma unroll
                for (int j = 0; j < 4; ++j) acc[q * 4 + j] += a[j];
            }
        }
        if (sub == 0) {
            const float* ep = E + (size_t)row * 16;
#pragma unroll
            for (int k = 0; k < 16; ++k) acc[k] += ep[k];
        }
    }
#pragma unroll
    for (int m = 1; m <= 2; m <<= 1)
#pragma unroll
        for (int k = 0; k < 16; ++k) acc[k] += __shfl_xor(acc[k], m, 4);
    if (LAST) {
        if (valid) {
            f32x4 oq = {acc[sub*4+0] + INV_C, acc[sub*4+1] + INV_C,
                        acc[sub*4+2] + INV_C, acc[sub*4+3] + INV_C};
            *(f32x4*)(out + (size_t)row * 16 + sub * 4) = oq;
        }
    } else {
        if (!valid) {
#pragma unroll
            for (int k = 0; k < 16; ++k) acc[k] = 0.f;
        }
        float o[4] = {0.f, 0.f, 0.f, 0.f};
#pragma unroll
        for (int m2 = 0; m2 < 16; ++m2) {
            float x = acc[m2];
#pragma unroll
            for (int j = 0; j < 4; ++j) o[j] += x * Hs[m2 * 16 + sub * 4 + j];
        }
#pragma unroll
        for (int j = 0; j < 4; ++j)
            bhT[(size_t)(sub * 4 + j) * KP + row] = f2b(o[j]);
    }
}

extern "C" void kernel_launch(void* const* d_in, const int* in_sizes, int n_in,
                              void* d_out, int out_size, void* d_ws, size_t ws_size,
                              hipStream_t stream)
{
    const float* raw_adj    = (const float*)d_in[0];
    const float* normed_adj = (const float*)d_in[1];
    const float* features   = (const float*)d_in[2];
    const float* W1 = (const float*)d_in[5];
    const float* b1 = (const float*)d_in[6];
    const float* W2 = (const float*)d_in[7];
    const float* b2 = (const float*)d_in[8];
    const float* H  = (const float*)d_in[9];
    float* out = (float*)d_out;

    char* ws = (char*)d_ws;
    // P fp32 [16][NN][16] = 10,240,000 @0 ; featbf (10,240,000) aliases P
    float* P      = (float*)(ws + 0);
    u16*   featbf = (u16*)  (ws + 0);
    float* E      = (float*)(ws + 10240000);          //    640,000
    float* W1T    = (float*)(ws + 10880000);          //    524,288
    u16*   XWT    = (u16*)  (ws + 11404288);          //  5,144,576
    u16*   hw2T   = (u16*)  (ws + 16548864);          //    321,536
    u16*   bhT    = (u16*)  (ws + 16870400);          //    321,536
    // big region @ 17,191,936:
    //   ArBf bf16 [NN][KP]: 200,960,000 -> end 218,151,936
    //   Pws13 bf16: 66,560,000 @ 218,151,936 -> end 284,711,936
    const bool full = ws_size >= (size_t)284711936;
    const bool low  = ws_size >= (size_t)83751936;    // Pws13 only
    u16* ArBf = (u16*)(ws + 17191936);
    u16* Pws  = (u16*)(ws + (full ? 218151936 : 17191936));

    // 1) conversions / transposes
    cvt_feat<<<2500, 256, 0, stream>>>(features, featbf);
    w1t<<<512, 256, 0, stream>>>(W1, W1T);

    // 2) XWT[256][KP] = (features @ W1)^T
    gemm_a32_bt16<0, 0><<<dim3(4, 40), 256, 0, stream>>>(
        W1T, 512, 256, 512, featbf, 512, NN, KP, nullptr, XWT, KP, 512);

    // 3) h-pass: counted-vmcnt split-K + fused relu/bias + @W2 -> hw2T
    if (low) {
        gemm_na<<<dim3(157, 13), 256, 0, stream>>>(normed_adj, XWT, Pws);
        reduce_h2<13><<<1251, 256, 0, stream>>>(Pws, b1, W2, hw2T);
    } else {
        u16* plane = (u16*)(ws + 17191936);
        gemm_a32_bt16<0, 0><<<dim3(157, 1), 256, 0, stream>>>(
            normed_adj, NN, NN, NN, XWT, KP, 256, 256, nullptr, plane, 256, KP);
        reduce_h2<1><<<1251, 256, 0, stream>>>((const u16*)plane, b1, W2, hw2T);
    }

    // 4) logits partials = normed_adj @ hw2 (fp32 stream, 16-way)
    adj16<1, 0><<<dim3(157, 16), 256, 0, stream>>>(
        (const void*)normed_adj, NN, hw2T, P, 313, 312, nullptr);

    // 5) softmax -> E ; bhT0 = (E @ H)^T
    softmax_e_h2<<<157, 256, 0, stream>>>(P, b2, H, E, bhT);

    // 6) 4 belief-propagation iterations (bf16 MFMA, 16-way)
    for (int it = 0; it < 4; ++it) {
        if (full) {
            if (it == 0)
                adj16<1, 1><<<dim3(157, 16), 256, 0, stream>>>(
                    (const void*)raw_adj, NN, bhT, P, 314, 312, ArBf);
            else
                adj16<0, 0><<<dim3(157, 16), 256, 0, stream>>>(
                    (const void*)ArBf, KP, bhT, P, 314, 314, nullptr);
        } else {
            adj16<1, 0><<<dim3(157, 16), 256, 0, stream>>>(
                (const void*)raw_adj, NN, bhT, P, 313, 312, nullptr);
        }
        if (it == 3)
            combine_bmm2<1><<<157, 256, 0, stream>>>(E, P, H, nullptr, out);
        else
            combine_bmm2<0><<<157, 256, 0, stream>>>(E, P, H, bhT, nullptr);
    }
}

// Round 11
// 591.824 us; speedup vs baseline: 1.0563x; 1.0563x over previous
//
#include <hip/hip_runtime.h>
#include <hip/hip_bf16.h>

#define NN 10000
#define KP 10048           // NN padded to multiple of 64
static constexpr float INV_C = 1.0f / 16.0f;

typedef __attribute__((ext_vector_type(8))) short bf16x8;
typedef __attribute__((ext_vector_type(4))) float f32x4;
typedef unsigned short u16;
typedef unsigned int u32;

// hardware RNE f32 -> bf16 (compiler emits v_cvt_pk_bf16_f32 pairs)
__device__ __forceinline__ u16 f2b(float f) {
    return __builtin_bit_cast(u16, __float2bfloat16(f));
}
__device__ __forceinline__ float b2f(u16 b) {
    union { u32 u; float f; } v; v.u = ((u32)b) << 16;
    return v.f;
}
__device__ __forceinline__ bf16x8 pack8(f32x4 a, f32x4 b) {
    bf16x8 o;
    o[0]=f2b(a[0]); o[1]=f2b(a[1]); o[2]=f2b(a[2]); o[3]=f2b(a[3]);
    o[4]=f2b(b[0]); o[5]=f2b(b[1]); o[6]=f2b(b[2]); o[7]=f2b(b[3]);
    return o;
}

#define AS1(p) ((__attribute__((address_space(1))) void*)(p))
#define AS3(p) ((__attribute__((address_space(3))) void*)(p))

// ---------------------------------------------------------------
// cvt_feat: fp32 [NN][512] -> bf16 [NN][512]; grid 2500 exact
// ---------------------------------------------------------------
__global__ __launch_bounds__(256)
void cvt_feat(const float* __restrict__ src, u16* __restrict__ dst)
{
    int c = blockIdx.x * 256 + threadIdx.x;
    size_t base = (size_t)c * 8;
    f32x4 a = *(const f32x4*)(src + base);
    f32x4 b = *(const f32x4*)(src + base + 4);
    *(bf16x8*)(dst + base) = pack8(a, b);
}

// ---------------------------------------------------------------
// w12t: W1T fp32 [256][512] <- W1 [512][256];  W2T bf16 [16][256] <- W2 [256][16]
// ---------------------------------------------------------------
__global__ __launch_bounds__(256)
void w12t(const float* __restrict__ W1, const float* __restrict__ W2,
          float* __restrict__ W1T, u16* __restrict__ W2T)
{
    int bid = blockIdx.x, t = threadIdx.x;
    if (bid < 512) {
        int idx = bid * 256 + t;           // n*512 + k
        int n = idx >> 9, k = idx & 511;
        W1T[idx] = W1[(size_t)k * 256 + n];
    } else {
        int idx = (bid - 512) * 256 + t;
        if (idx < 4096) {
            int n_ = idx >> 8, k_ = idx & 255;
            W2T[idx] = f2b(W2[(size_t)k_ * 16 + n_]);
        }
    }
}

// ---------------------------------------------------------------
// Generic MFMA GEMM (XWT; also ultra-low fallback):
// C[M][N] = A(fp32)[M][lda] @ B, B transposed bf16 BT[N][ldb].
// BM=64, BN=256, BK=64; 256 thr = 4 waves.
// ---------------------------------------------------------------
template<int BIAS, int RELU>
__global__ __launch_bounds__(256)
void gemm_a32_bt16(const float* __restrict__ A, int lda, int M, int Ka,
                   const u16* __restrict__ BT, int ldb, int N, int npad,
                   const float* __restrict__ bias,
                   u16* __restrict__ C, int ldc, int K)
{
    __shared__ u16 Asm[64 * 64];
    __shared__ u16 Bsm[256 * 64];
    const int t = threadIdx.x;
    const int lane = t & 63;
    const int w = t >> 6;
    const int row0 = blockIdx.x * 64;
    const int n0 = blockIdx.y * 256;

    const f32x4 fz = {0.f, 0.f, 0.f, 0.f};
    f32x4 acc[4][4];
#pragma unroll
    for (int i = 0; i < 4; ++i)
#pragma unroll
        for (int j = 0; j < 4; ++j) acc[i][j] = fz;

    const int ar = t >> 2, akq = t & 3;
    int agr = row0 + ar; if (agr > M - 1) agr = M - 1;
    const float* asrc = A + (size_t)agr * lda + akq * 16;
    const int aslot0 = (akq * 2) ^ (ar & 7);
    const int aslot1 = (akq * 2 + 1) ^ (ar & 7);
    const int l8 = lane >> 3, sl = lane & 7;

    for (int k0 = 0; k0 < K; k0 += 64) {
        bool aval = (k0 + akq * 16) < Ka;
        f32x4 x0, x1, x2, x3;
        if (aval) {
            x0 = *(const f32x4*)(asrc + k0);
            x1 = *(const f32x4*)(asrc + k0 + 4);
            x2 = *(const f32x4*)(asrc + k0 + 8);
            x3 = *(const f32x4*)(asrc + k0 + 12);
        } else {
            x0 = x1 = x2 = x3 = fz;
        }
#pragma unroll
        for (int i = 0; i < 8; ++i) {
            int lr = i * 32 + w * 8 + l8;
            int gn = n0 + lr; if (gn > N - 1) gn = N - 1;
            int ss = sl ^ (lr & 7);
            const u16* src = BT + (size_t)gn * ldb + k0 + ss * 8;
            __builtin_amdgcn_global_load_lds(AS1(src), AS3(&Bsm[(i * 32 + w * 8) * 64]),
                                             16, 0, 0);
        }
        *(bf16x8*)&Asm[ar * 64 + aslot0 * 8] = pack8(x0, x1);
        *(bf16x8*)&Asm[ar * 64 + aslot1 * 8] = pack8(x2, x3);
        __syncthreads();
#pragma unroll
        for (int kk = 0; kk < 2; ++kk) {
            bf16x8 afr[4], bfr[4];
#pragma unroll
            for (int mi = 0; mi < 4; ++mi) {
                int r = mi * 16 + (lane & 15);
                int s2 = (kk * 4 + (lane >> 4)) ^ (r & 7);
                afr[mi] = *(const bf16x8*)&Asm[r * 64 + s2 * 8];
            }
#pragma unroll
            for (int ni = 0; ni < 4; ++ni) {
                int nr = w * 64 + ni * 16 + (lane & 15);
                int s2 = (kk * 4 + (lane >> 4)) ^ (nr & 7);
                bfr[ni] = *(const bf16x8*)&Bsm[nr * 64 + s2 * 8];
            }
#pragma unroll
            for (int mi = 0; mi < 4; ++mi)
#pragma unroll
                for (int ni = 0; ni < 4; ++ni)
                    acc[mi][ni] = __builtin_amdgcn_mfma_f32_16x16x32_bf16(
                        afr[mi], bfr[ni], acc[mi][ni], 0, 0, 0);
        }
        __syncthreads();
    }
#pragma unroll
    for (int mi = 0; mi < 4; ++mi) {
        int grb = row0 + mi * 16 + (lane >> 4) * 4;
#pragma unroll
        for (int ni = 0; ni < 4; ++ni) {
            int gc = n0 + w * 64 + ni * 16 + (lane & 15);
            if (gc < npad) {
                float bv = (BIAS && gc < N) ? bias[gc] : 0.f;
#pragma unroll
                for (int rg = 0; rg < 4; ++rg) {
                    int gr = grb + rg;
                    if (gr < M) {
                        float v = acc[mi][ni][rg] + bv;
                        if (RELU) v = fmaxf(v, 0.f);
                        C[(size_t)gr * ldc + gc] = f2b(gc < N ? v : 0.f);
                    }
                }
            }
        }
    }
}

// ---------------------------------------------------------------
// gemm_na: 16-way split-K pass over normed_adj, A-prefetch pipelined.
// Pws16[s][NN][256] (bf16 partials). grid (157, 16). BT = XWT bf16.
// K-step: {gload_lds B(ck); ds_write A(ck) from regs} bar1
//         {issue A(ck+1) reg loads; 32 MFMA} bar2  -> A latency hides
// ---------------------------------------------------------------
__global__ __launch_bounds__(256)
void gemm_na(const float* __restrict__ A, const u16* __restrict__ BT,
             u16* __restrict__ Pws)
{
    __shared__ u16 Asm[64 * 64];
    __shared__ u16 Bsm[256 * 64];
    const int t = threadIdx.x;
    const int lane = t & 63;
    const int w = t >> 6;
    const int row0 = blockIdx.x * 64;
    const int s = blockIdx.y;
    const int c0 = (157 * s) >> 4, c1 = (157 * (s + 1)) >> 4;

    const f32x4 fz = {0.f, 0.f, 0.f, 0.f};
    f32x4 acc[4][4];
#pragma unroll
    for (int i = 0; i < 4; ++i)
#pragma unroll
        for (int j = 0; j < 4; ++j) acc[i][j] = fz;

    const int ar = t >> 2, akq = t & 3;
    const int grow = row0 + ar;
    const int agr = grow < NN ? grow : NN - 1;
    const float* asrc = A + (size_t)agr * NN + akq * 16;
    const int aslot0 = (akq * 2) ^ (ar & 7);
    const int aslot1 = (akq * 2 + 1) ^ (ar & 7);
    const int l8 = lane >> 3, sl = lane & 7;

    // prologue: load A(c0)
    f32x4 x0, x1, x2, x3;
    {
        const int k0 = c0 * 64;
        if (k0 + akq * 16 < NN) {
            x0 = *(const f32x4*)(asrc + k0);
            x1 = *(const f32x4*)(asrc + k0 + 4);
            x2 = *(const f32x4*)(asrc + k0 + 8);
            x3 = *(const f32x4*)(asrc + k0 + 12);
        } else {
            x0 = x1 = x2 = x3 = fz;
        }
    }

    for (int ck = c0; ck < c1; ++ck) {
        const int k0 = ck * 64;
#pragma unroll
        for (int i = 0; i < 8; ++i) {
            int lr = i * 32 + w * 8 + l8;
            int ss = sl ^ (lr & 7);
            const u16* src = BT + (size_t)lr * KP + k0 + ss * 8;
            __builtin_amdgcn_global_load_lds(AS1(src), AS3(&Bsm[(i * 32 + w * 8) * 64]),
                                             16, 0, 0);
        }
        *(bf16x8*)&Asm[ar * 64 + aslot0 * 8] = pack8(x0, x1);
        *(bf16x8*)&Asm[ar * 64 + aslot1 * 8] = pack8(x2, x3);
        __syncthreads();
        // prefetch A(ck+1) — flies during the MFMA phase
        {
            const int kn = k0 + 64;
            if (ck + 1 < c1 && (kn + akq * 16) < NN) {
                x0 = *(const f32x4*)(asrc + kn);
                x1 = *(const f32x4*)(asrc + kn + 4);
                x2 = *(const f32x4*)(asrc + kn + 8);
                x3 = *(const f32x4*)(asrc + kn + 12);
            } else {
                x0 = x1 = x2 = x3 = fz;
            }
        }
#pragma unroll
        for (int kk = 0; kk < 2; ++kk) {
            bf16x8 afr[4], bfr[4];
#pragma unroll
            for (int mi = 0; mi < 4; ++mi) {
                int r = mi * 16 + (lane & 15);
                int s2 = (kk * 4 + (lane >> 4)) ^ (r & 7);
                afr[mi] = *(const bf16x8*)&Asm[r * 64 + s2 * 8];
            }
#pragma unroll
            for (int ni = 0; ni < 4; ++ni) {
                int nr = w * 64 + ni * 16 + (lane & 15);
                int s2 = (kk * 4 + (lane >> 4)) ^ (nr & 7);
                bfr[ni] = *(const bf16x8*)&Bsm[nr * 64 + s2 * 8];
            }
#pragma unroll
            for (int mi = 0; mi < 4; ++mi)
#pragma unroll
                for (int ni = 0; ni < 4; ++ni)
                    acc[mi][ni] = __builtin_amdgcn_mfma_f32_16x16x32_bf16(
                        afr[mi], bfr[ni], acc[mi][ni], 0, 0, 0);
        }
        __syncthreads();
    }
    u16* outp = Pws + (size_t)s * NN * 256;
#pragma unroll
    for (int mi = 0; mi < 4; ++mi) {
        int grb = row0 + mi * 16 + (lane >> 4) * 4;
#pragma unroll
        for (int ni = 0; ni < 4; ++ni) {
            int gc = w * 64 + ni * 16 + (lane & 15);
#pragma unroll
            for (int rg = 0; rg < 4; ++rg) {
                int gr = grb + rg;
                if (gr < NN)
                    outp[(size_t)gr * 256 + gc] = f2b(acc[mi][ni][rg]);
            }
        }
    }
}

// ---------------------------------------------------------------
// reduce_h: hbf = relu(sum_{s<16} Pws16[s] + b1) -> bf16 [NN][256]; grid 1250
// ---------------------------------------------------------------
__global__ __launch_bounds__(256)
void reduce_h(const u16* __restrict__ Pws, const float* __restrict__ b1,
              u16* __restrict__ hbf)
{
    int i8 = blockIdx.x * 256 + threadIdx.x;
    size_t base = (size_t)i8 * 8;
    int col = (int)(base & 255);
    float v[8];
#pragma unroll
    for (int j = 0; j < 8; ++j) v[j] = b1[col + j];
#pragma unroll
    for (int s = 0; s < 16; ++s) {
        bf16x8 p = *(const bf16x8*)(Pws + (size_t)s * NN * 256 + base);
#pragma unroll
        for (int j = 0; j < 8; ++j) v[j] += b2f((u16)p[j]);
    }
    bf16x8 o;
#pragma unroll
    for (int j = 0; j < 8; ++j) o[j] = f2b(fmaxf(v[j], 0.f));
    *(bf16x8*)(hbf + base) = o;
}

// ---------------------------------------------------------------
// adj16: Pout[s][i][c] = sum_{j in s-range} A[i][j] * BT[c][j]
// AFP32: A fp32 (on-the-fly cvt) else bf16 [*,KP]. CVT: write bf16 copy.
// grid (157, 8), 4 waves x 16 rows. Dual accumulators for MFMA ILP.
// ---------------------------------------------------------------
template<int AFP32, int CVT>
__global__ __launch_bounds__(256)
void adj16(const void* __restrict__ Av, long lda,
           const u16* __restrict__ BT,
           float* __restrict__ Pout, int nch, int nchf,
           u16* __restrict__ Acvt)
{
    const int t = threadIdx.x, lane = t & 63, w = t >> 6;
    const int s = blockIdx.y;
    const int rowu = blockIdx.x * 64 + w * 16 + (lane & 15);
    const int row = rowu < NN ? rowu : NN - 1;
    const int kq = (lane >> 4) * 8;
    const u16* brow = BT + (size_t)(lane & 15) * KP + kq;
    const float* a32 = (const float*)Av + (size_t)row * lda + kq;
    const u16*  a16 = (const u16*) Av + (size_t)row * lda + kq;
    u16* cvtp = CVT ? (Acvt + (size_t)rowu * KP + kq) : (u16*)0;
    const bool wok = CVT && (rowu < NN);

    int c0 = (nch * s) >> 3, c1 = (nch * (s + 1)) >> 3;
    int c1f = c1 < nchf ? c1 : nchf;
    f32x4 acc0 = {0.f, 0.f, 0.f, 0.f};
    f32x4 acc1 = {0.f, 0.f, 0.f, 0.f};
    int kc = c0;
    for (; kc + 4 <= c1f; kc += 4) {
        bf16x8 a[4], b[4];
#pragma unroll
        for (int u = 0; u < 4; ++u) {
            if (AFP32) {
                f32x4 x = *(const f32x4*)(a32 + (size_t)(kc + u) * 32);
                f32x4 y = *(const f32x4*)(a32 + (size_t)(kc + u) * 32 + 4);
                a[u] = pack8(x, y);
            } else {
                a[u] = *(const bf16x8*)(a16 + (size_t)(kc + u) * 32);
            }
            b[u] = *(const bf16x8*)(brow + (size_t)(kc + u) * 32);
        }
        if (CVT && wok) {
#pragma unroll
            for (int u = 0; u < 4; ++u)
                *(bf16x8*)(cvtp + (size_t)(kc + u) * 32) = a[u];
        }
        acc0 = __builtin_amdgcn_mfma_f32_16x16x32_bf16(a[0], b[0], acc0, 0, 0, 0);
        acc1 = __builtin_amdgcn_mfma_f32_16x16x32_bf16(a[1], b[1], acc1, 0, 0, 0);
        acc0 = __builtin_amdgcn_mfma_f32_16x16x32_bf16(a[2], b[2], acc0, 0, 0, 0);
        acc1 = __builtin_amdgcn_mfma_f32_16x16x32_bf16(a[3], b[3], acc1, 0, 0, 0);
    }
    for (; kc < c1; ++kc) {
        bf16x8 a = bf16x8{0,0,0,0,0,0,0,0};
        if (AFP32) {
            if (kc * 32 + kq < NN) {
                f32x4 x = *(const f32x4*)(a32 + (size_t)kc * 32);
                f32x4 y = *(const f32x4*)(a32 + (size_t)kc * 32 + 4);
                a = pack8(x, y);
            }
        } else {
            a = *(const bf16x8*)(a16 + (size_t)kc * 32);
        }
        if (CVT && wok)
            *(bf16x8*)(cvtp + (size_t)kc * 32) = a;
        bf16x8 b = *(const bf16x8*)(brow + (size_t)kc * 32);
        acc0 = __builtin_amdgcn_mfma_f32_16x16x32_bf16(a, b, acc0, 0, 0, 0);
    }
    int ob = blockIdx.x * 64 + w * 16 + (lane >> 4) * 4;
#pragma unroll
    for (int rg = 0; rg < 4; ++rg) {
        int orow = ob + rg;
        if (orow < NN)
            Pout[(size_t)s * (NN * 16) + (size_t)orow * 16 + (lane & 15)] =
                acc0[rg] + acc1[rg];
    }
}

// ---------------------------------------------------------------
// hw2_mfma: outT[16][KP] = (h[NN][256] @ W2)^T via W2T bf16 [16][256]
// ---------------------------------------------------------------
__global__ __launch_bounds__(256)
void hw2_mfma(const u16* __restrict__ h, const u16* __restrict__ W2T,
              u16* __restrict__ outT)
{
    const int t = threadIdx.x, lane = t & 63, w = t >> 6;
    int row = blockIdx.x * 64 + w * 16 + (lane & 15);
    int rowc = row < NN ? row : NN - 1;
    const int kq = (lane >> 4) * 8;
    const u16* arow = h + (size_t)rowc * 256 + kq;
    const u16* brow = W2T + (size_t)(lane & 15) * 256 + kq;
    f32x4 acc = {0.f, 0.f, 0.f, 0.f};
#pragma unroll
    for (int kc = 0; kc < 8; ++kc) {
        bf16x8 a = *(const bf16x8*)(arow + kc * 32);
        bf16x8 b = *(const bf16x8*)(brow + kc * 32);
        acc = __builtin_amdgcn_mfma_f32_16x16x32_bf16(a, b, acc, 0, 0, 0);
    }
    int ob = blockIdx.x * 64 + w * 16 + (lane >> 4) * 4;
    int col = lane & 15;
#pragma unroll
    for (int rg = 0; rg < 4; ++rg) {
        int r = ob + rg;
        outT[(size_t)col * KP + r] = f2b(r < NN ? acc[rg] : 0.f);
    }
}

// ---------------------------------------------------------------
// softmax_e_h2: 4 lanes per row, grid 157 (157*64 = KP rows).
// logits = sum_s P[s] + b2 -> E = softmax - 1/16 ; bhT = (E@H)^T bf16.
// ---------------------------------------------------------------
__global__ __launch_bounds__(256)
void softmax_e_h2(const float* __restrict__ P, const float* __restrict__ b2,
                  const float* __restrict__ H, float* __restrict__ E,
                  u16* __restrict__ bhT)
{
    __shared__ float Hs[256];
    const int t = threadIdx.x;
    Hs[t] = H[t];
    __syncthreads();
    const int l = t & 63, w = t >> 6;
    const int g = l >> 2, sub = l & 3;
    const int row = blockIdx.x * 64 + w * 16 + g;
    const bool valid = row < NN;
    float acc[16];
#pragma unroll
    for (int k = 0; k < 16; ++k) acc[k] = 0.f;
    if (valid) {
        const float* p0 = P + (size_t)(sub * 2) * (NN * 16) + (size_t)row * 16;
        const float* p1 = p0 + (size_t)NN * 16;
#pragma unroll
        for (int q = 0; q < 4; ++q) {
            f32x4 a = *(const f32x4*)(p0 + q * 4);
            f32x4 c = *(const f32x4*)(p1 + q * 4);
#pragma unroll
            for (int j = 0; j < 4; ++j) acc[q * 4 + j] = a[j] + c[j];
        }
        if (sub == 0) {
#pragma unroll
            for (int k = 0; k < 16; ++k) acc[k] += b2[k];
        }
    }
#pragma unroll
    for (int m = 1; m <= 2; m <<= 1)
#pragma unroll
        for (int k = 0; k < 16; ++k) acc[k] += __shfl_xor(acc[k], m, 4);
    float e[16];
    if (valid) {
        float mx = acc[0];
#pragma unroll
        for (int k = 1; k < 16; ++k) mx = fmaxf(mx, acc[k]);
        float ssum = 0.f;
#pragma unroll
        for (int k = 0; k < 16; ++k) { e[k] = __expf(acc[k] - mx); ssum += e[k]; }
        float inv = 1.f / ssum;
#pragma unroll
        for (int k = 0; k < 16; ++k) e[k] = e[k] * inv - INV_C;
        f32x4 eq = {e[sub*4+0], e[sub*4+1], e[sub*4+2], e[sub*4+3]};
        *(f32x4*)(E + (size_t)row * 16 + sub * 4) = eq;
    } else {
#pragma unroll
        for (int k = 0; k < 16; ++k) e[k] = 0.f;
    }
    float o[4] = {0.f, 0.f, 0.f, 0.f};
#pragma unroll
    for (int m2 = 0; m2 < 16; ++m2) {
        float x = e[m2];
#pragma unroll
        for (int j = 0; j < 4; ++j) o[j] += x * Hs[m2 * 16 + sub * 4 + j];
    }
#pragma unroll
    for (int j = 0; j < 4; ++j)
        bhT[(size_t)(sub * 4 + j) * KP + row] = f2b(o[j]);
}

// ---------------------------------------------------------------
// combine_bmm2: 4 lanes per row, grid 157. B = E + sum_s P[s];
// LAST: out = B + 1/16 (fp32). else: bhT = (B @ H)^T bf16.
// ---------------------------------------------------------------
template<int LAST>
__global__ __launch_bounds__(256)
void combine_bmm2(const float* __restrict__ E, const float* __restrict__ P,
                  const float* __restrict__ H, u16* __restrict__ bhT,
                  float* __restrict__ out)
{
    __shared__ float Hs[256];
    const int t = threadIdx.x;
    Hs[t] = H[t];
    __syncthreads();
    const int l = t & 63, w = t >> 6;
    const int g = l >> 2, sub = l & 3;
    const int row = blockIdx.x * 64 + w * 16 + g;
    const bool valid = row < NN;
    float acc[16];
#pragma unroll
    for (int k = 0; k < 16; ++k) acc[k] = 0.f;
    if (valid) {
        const float* p0 = P + (size_t)(sub * 2) * (NN * 16) + (size_t)row * 16;
        const float* p1 = p0 + (size_t)NN * 16;
#pragma unroll
        for (int q = 0; q < 4; ++q) {
            f32x4 a = *(const f32x4*)(p0 + q * 4);
            f32x4 c = *(const f32x4*)(p1 + q * 4);
#pragma unroll
            for (int j = 0; j < 4; ++j) acc[q * 4 + j] = a[j] + c[j];
        }
        if (sub == 0) {
            const float* ep = E + (size_t)row * 16;
#pragma unroll
            for (int k = 0; k < 16; ++k) acc[k] += ep[k];
        }
    }
#pragma unroll
    for (int m = 1; m <= 2; m <<= 1)
#pragma unroll
        for (int k = 0; k < 16; ++k) acc[k] += __shfl_xor(acc[k], m, 4);
    if (LAST) {
        if (valid) {
            f32x4 oq = {acc[sub*4+0] + INV_C, acc[sub*4+1] + INV_C,
                        acc[sub*4+2] + INV_C, acc[sub*4+3] + INV_C};
            *(f32x4*)(out + (size_t)row * 16 + sub * 4) = oq;
        }
    } else {
        if (!valid) {
#pragma unroll
            for (int k = 0; k < 16; ++k) acc[k] = 0.f;
        }
        float o[4] = {0.f, 0.f, 0.f, 0.f};
#pragma unroll
        for (int m2 = 0; m2 < 16; ++m2) {
            float x = acc[m2];
#pragma unroll
            for (int j = 0; j < 4; ++j) o[j] += x * Hs[m2 * 16 + sub * 4 + j];
        }
#pragma unroll
        for (int j = 0; j < 4; ++j)
            bhT[(size_t)(sub * 4 + j) * KP + row] = f2b(o[j]);
    }
}

extern "C" void kernel_launch(void* const* d_in, const int* in_sizes, int n_in,
                              void* d_out, int out_size, void* d_ws, size_t ws_size,
                              hipStream_t stream)
{
    const float* raw_adj    = (const float*)d_in[0];
    const float* normed_adj = (const float*)d_in[1];
    const float* features   = (const float*)d_in[2];
    const float* W1 = (const float*)d_in[5];
    const float* b1 = (const float*)d_in[6];
    const float* W2 = (const float*)d_in[7];
    const float* b2 = (const float*)d_in[8];
    const float* H  = (const float*)d_in[9];
    float* out = (float*)d_out;

    char* ws = (char*)d_ws;
    // fixed small region (featbf aliased later by P/E)
    u16*   featbf = (u16*)  (ws + 0);                 // 10,240,000
    float* P      = (float*)(ws + 0);                 //  5,120,000 (alias)
    float* E      = (float*)(ws + 5120000);           //    640,000 (alias)
    float* W1T    = (float*)(ws + 10240000);          //    524,288
    u16*   W2T    = (u16*)  (ws + 10764288);          //      8,192
    u16*   XWT    = (u16*)  (ws + 10772480);          //  5,144,576
    u16*   hbf    = (u16*)  (ws + 15917056);          //  5,120,000
    u16*   hw2T   = (u16*)  (ws + 21037056);          //    321,536
    u16*   bhT    = (u16*)  (ws + 21358592);          //    321,536
    // big region @ 21,680,128 — Pws16 (81,920,000) and ArBf (200,960,000)
    // ALIAS: Pws is dead after reduce_h, before ArBf is first written (it0).
    const bool mid = ws_size >= (size_t)222640128;    // ArBf fits
    const bool low = ws_size >= (size_t)103600128;    // Pws16 fits
    u16* Pws  = (u16*)(ws + 21680128);
    u16* ArBf = (u16*)(ws + 21680128);

    // 1) conversions / transposes
    cvt_feat<<<2500, 256, 0, stream>>>(features, featbf);
    w12t<<<528, 256, 0, stream>>>(W1, W2, W1T, W2T);

    // 2) XWT[256][KP] = (features @ W1)^T
    gemm_a32_bt16<0, 0><<<dim3(4, 40), 256, 0, stream>>>(
        W1T, 512, 256, 512, featbf, 512, NN, KP, nullptr, XWT, KP, 512);

    // 3) h = relu(normed_adj @ XW + b1)
    if (low) {
        gemm_na<<<dim3(157, 16), 256, 0, stream>>>(normed_adj, XWT, Pws);
        reduce_h<<<1250, 256, 0, stream>>>(Pws, b1, hbf);
    } else {
        gemm_a32_bt16<1, 1><<<dim3(157, 1), 256, 0, stream>>>(
            normed_adj, NN, NN, NN, XWT, KP, 256, 256, b1, hbf, 256, KP);
    }

    // 4) hw2T = (h @ W2)^T
    hw2_mfma<<<157, 256, 0, stream>>>(hbf, W2T, hw2T);

    // 5) logits partials = normed_adj @ hw2  (pure fp32 stream)
    adj16<1, 0><<<dim3(157, 8), 256, 0, stream>>>(
        (const void*)normed_adj, NN, hw2T, P, 313, 312, nullptr);

    // 6) softmax -> E ; bhT0 = (E @ H)^T
    softmax_e_h2<<<157, 256, 0, stream>>>(P, b2, H, E, bhT);

    // 7) 4 belief-propagation iterations
    for (int it = 0; it < 4; ++it) {
        if (mid) {
            if (it == 0)
                adj16<1, 1><<<dim3(157, 8), 256, 0, stream>>>(
                    (const void*)raw_adj, NN, bhT, P, 314, 312, ArBf);
            else
                adj16<0, 0><<<dim3(157, 8), 256, 0, stream>>>(
                    (const void*)ArBf, KP, bhT, P, 314, 314, nullptr);
        } else {
            adj16<1, 0><<<dim3(157, 8), 256, 0, stream>>>(
                (const void*)raw_adj, NN, bhT, P, 313, 312, nullptr);
        }
        if (it == 3)
            combine_bmm2<1><<<157, 256, 0, stream>>>(E, P, H, nullptr, out);
        else
            combine_bmm2<0><<<157, 256, 0, stream>>>(E, P, H, bhT, nullptr);
    }
}